// Round 3
// baseline (1623.470 us; speedup 1.0000x reference)
//
#include <hip/hip_runtime.h>
#include <cstdint>
#include <cstddef>

#define TLEN 512
#define BATCH 1000
#define NEVS 102400   // events per source
#define HID 64
#define W0S 32        // fused0 window steps per phase (512 % 32 == 0)

__device__ __forceinline__ float fast_rcp(float x) {
#if __has_builtin(__builtin_amdgcn_rcpf)
    return __builtin_amdgcn_rcpf(x);
#else
    return 1.0f / x;
#endif
}
__device__ __forceinline__ float sigm(float x) { return fast_rcp(1.0f + __expf(-x)); }
__device__ __forceinline__ float tanh_f(float x) { return fmaf(2.0f, sigm(2.0f * x), -1.0f); }

// Wave-wide sum broadcast (rocPRIM gfx9 DPP pattern).
__device__ __forceinline__ float wave_sum_bcast(float x) {
#if __has_builtin(__builtin_amdgcn_update_dpp) && __has_builtin(__builtin_amdgcn_readlane)
    x += __int_as_float(__builtin_amdgcn_update_dpp(0, __float_as_int(x), 0x111, 0xf, 0xf, true)); // row_shr:1
    x += __int_as_float(__builtin_amdgcn_update_dpp(0, __float_as_int(x), 0x112, 0xf, 0xf, true)); // row_shr:2
    x += __int_as_float(__builtin_amdgcn_update_dpp(0, __float_as_int(x), 0x114, 0xf, 0xf, true)); // row_shr:4
    x += __int_as_float(__builtin_amdgcn_update_dpp(0, __float_as_int(x), 0x118, 0xf, 0xf, true)); // row_shr:8
    x += __int_as_float(__builtin_amdgcn_update_dpp(0, __float_as_int(x), 0x142, 0xa, 0xf, true)); // row_bcast:15
    x += __int_as_float(__builtin_amdgcn_update_dpp(0, __float_as_int(x), 0x143, 0xc, 0xf, true)); // row_bcast:31
    return __int_as_float(__builtin_amdgcn_readlane(__float_as_int(x), 63));
#else
#pragma unroll
    for (int off = 1; off < 64; off <<= 1) x += __shfl_xor(x, off, 64);
    return x;
#endif
}

// ===========================================================================
// map[b*512+t] = src<<20 | e  (sources partition the (b,t) grid: exactly one)
// ===========================================================================
__global__ __launch_bounds__(256) void map_build_kernel(
    const int* __restrict__ b0, const int* __restrict__ t0,
    const int* __restrict__ b1, const int* __restrict__ t1,
    const int* __restrict__ b2, const int* __restrict__ t2,
    const int* __restrict__ b3, const int* __restrict__ t3,
    const int* __restrict__ b4, const int* __restrict__ t4,
    int* __restrict__ map)
{
    const int src = blockIdx.y;
    const int* bi = src == 0 ? b0 : src == 1 ? b1 : src == 2 ? b2 : src == 3 ? b3 : b4;
    const int* ti = src == 0 ? t0 : src == 1 ? t1 : src == 2 ? t2 : src == 3 ? t3 : t4;
    const int e = blockIdx.x * 256 + threadIdx.x;
    map[bi[e] * TLEN + ti[e]] = (src << 20) | e;
}

// ===========================================================================
// Composed projection weights: wp[row][col], row=(src,j) [130], col=dir*256+r.
// row j<IND: W_src[j] . Wih0[col]; row j==IND: b_src . Wih0[col] + bih+bhh.
// ===========================================================================
__global__ __launch_bounds__(512) void compose_kernel(
    const float* __restrict__ W0, const float* __restrict__ B0,
    const float* __restrict__ W1, const float* __restrict__ B1,
    const float* __restrict__ W2, const float* __restrict__ B2,
    const float* __restrict__ W3, const float* __restrict__ B3,
    const float* __restrict__ W4, const float* __restrict__ B4,
    const float* __restrict__ Wih, const float* __restrict__ bih,
    const float* __restrict__ bhh, float* __restrict__ wp)
{
    const int col = threadIdx.x;   // 0..511 == dir*256 + r == Wih row index
    const int row = blockIdx.x;    // 0..129
    const float* srcW; const float* srcB; int base, IND;
    if (row < 9)        { srcW = W0; srcB = B0; base = 0;   IND = 8;  }
    else if (row < 27)  { srcW = W1; srcB = B1; base = 9;   IND = 17; }
    else if (row < 53)  { srcW = W2; srcB = B2; base = 27;  IND = 25; }
    else if (row < 120) { srcW = W3; srcB = B3; base = 53;  IND = 66; }
    else                { srcW = W4; srcB = B4; base = 120; IND = 9;  }
    const int j = row - base;
    const float* xrow = (j < IND) ? (srcW + (size_t)j * 64) : srcB;
    const float* wr = Wih + (size_t)col * 64;
    float acc = 0.0f;
#pragma unroll
    for (int h2 = 0; h2 < 64; ++h2) acc = fmaf(xrow[h2], wr[h2], acc);
    if (j == IND) acc += bih[col] + bhh[col];
    wp[(size_t)row * 512 + col] = acc;
}

// ===========================================================================
// Fused layer-0: block = (b,dir), 256 threads (4 waves).
// Phase (W0S steps): A0 gather event inputs -> LDS xbuf (8 thr/event, ILP);
// A1 each thread = one gate column, dot(x, W'col) from registers -> window;
// B wave 0 runs W0S recurrence steps from window (1-step LDS prefetch).
// Gates never touch global memory; (h,c) stay in registers for all 512 steps.
// ===========================================================================
__global__ __launch_bounds__(256) void fused0_kernel(
    const float* __restrict__ ccba_num,
    const float* __restrict__ cdtx_num, const int* __restrict__ cdtx_cat, const float* __restrict__ cdtx_tab,
    const float* __restrict__ cust_num, const int* __restrict__ cust_cat, const float* __restrict__ cust_tab,
    const float* __restrict__ dp_num,   const int* __restrict__ dp_cat,   const float* __restrict__ dp_tab,
    const float* __restrict__ remit_num, const int* __restrict__ remit_cat, const float* __restrict__ remit_tab,
    const float* __restrict__ wp, const int* __restrict__ map,
    const float* __restrict__ Whh, const float* __restrict__ Whr,
    float* __restrict__ h0)
{
    const int tid = threadIdx.x;
    const int b = blockIdx.x >> 1, dir = blockIdx.x & 1;
    const int col = dir * 256 + tid;

    // Composed weight rows, per-source static arrays (statically indexed only).
    float w_c0[9], w_c1[18], w_c2[26], w_c3[67], w_c4[10];
#pragma unroll
    for (int j = 0; j < 9;  ++j) w_c0[j] = wp[(size_t)(0   + j) * 512 + col];
#pragma unroll
    for (int j = 0; j < 18; ++j) w_c1[j] = wp[(size_t)(9   + j) * 512 + col];
#pragma unroll
    for (int j = 0; j < 26; ++j) w_c2[j] = wp[(size_t)(27  + j) * 512 + col];
#pragma unroll
    for (int j = 0; j < 67; ++j) w_c3[j] = wp[(size_t)(53  + j) * 512 + col];
#pragma unroll
    for (int j = 0; j < 10; ++j) w_c4[j] = wp[(size_t)(120 + j) * 512 + col];

    __shared__ float window[W0S * 256];
    __shared__ float xbuf[W0S][68];
    __shared__ int   mcls[W0S];

    // consumer (wave 0) state
    const int lane = tid & 63;
    float whh4[4] = {0, 0, 0, 0};
    float whr = 0.0f, h = 0.0f, c = 0.0f;
    if (tid < 64) {
#pragma unroll
        for (int k = 0; k < 4; ++k) whh4[k] = Whh[dir * 256 + k * 64 + lane];
        whr = Whr[dir * HID + lane];
    }
    float* h0p = h0 + (size_t)b * TLEN * 2 + dir;

    // dot(x_event, W'col) with bias row; two chains for latency.
    auto dot_evt = [&](int mc, const float* xb) -> float {
        const int src = mc >> 20;
        float a0 = 0.0f, a1 = 0.0f, bias = 0.0f;
        switch (src) {
        case 0:
#pragma unroll
            for (int j = 0; j < 8; j += 2) { a0 = fmaf(xb[j], w_c0[j], a0); a1 = fmaf(xb[j + 1], w_c0[j + 1], a1); }
            bias = w_c0[8]; break;
        case 1:
#pragma unroll
            for (int j = 0; j < 16; j += 2) { a0 = fmaf(xb[j], w_c1[j], a0); a1 = fmaf(xb[j + 1], w_c1[j + 1], a1); }
            a0 = fmaf(xb[16], w_c1[16], a0);
            bias = w_c1[17]; break;
        case 2:
#pragma unroll
            for (int j = 0; j < 24; j += 2) { a0 = fmaf(xb[j], w_c2[j], a0); a1 = fmaf(xb[j + 1], w_c2[j + 1], a1); }
            a0 = fmaf(xb[24], w_c2[24], a0);
            bias = w_c2[25]; break;
        case 3:
#pragma unroll
            for (int j = 0; j < 66; j += 2) { a0 = fmaf(xb[j], w_c3[j], a0); a1 = fmaf(xb[j + 1], w_c3[j + 1], a1); }
            bias = w_c3[66]; break;
        default:
#pragma unroll
            for (int j = 0; j < 8; j += 2) { a0 = fmaf(xb[j], w_c4[j], a0); a1 = fmaf(xb[j + 1], w_c4[j + 1], a1); }
            a0 = fmaf(xb[8], w_c4[8], a0);
            bias = w_c4[9]; break;
        }
        return bias + a0 + a1;
    };

    for (int s0 = 0; s0 < TLEN; s0 += W0S) {
        // ---- A0: gather inputs for the W0S events of this phase ----
        {
            const int sl = tid >> 3, q = tid & 7;      // 32 events x 8 threads
            const int s = s0 + sl;
            const int t = dir ? (TLEN - 1 - s) : s;
            const int mc = map[b * TLEN + t];
            if (q == 0) mcls[sl] = mc;
            const int src = mc >> 20, e = mc & 0xFFFFF;
            switch (src) {
            case 0:
                for (int v = q; v < 8; v += 8) xbuf[sl][v] = ccba_num[(size_t)e * 8 + v];
                break;
            case 1:
                for (int v = q; v < 17; v += 8) {
                    float x = (v < 16) ? cdtx_tab[(size_t)cdtx_cat[e * 2 + (v >> 3)] * 8 + (v & 7)]
                                       : cdtx_num[e];
                    xbuf[sl][v] = x;
                }
                break;
            case 2:
                for (int v = q; v < 25; v += 8) {
                    float x = (v < 24) ? cust_tab[(size_t)cust_cat[e * 3 + (v >> 3)] * 8 + (v & 7)]
                                       : cust_num[e];
                    xbuf[sl][v] = x;
                }
                break;
            case 3:
                for (int v = q; v < 66; v += 8) {
                    float x = (v < 64) ? dp_tab[(size_t)dp_cat[e * 8 + (v >> 3)] * 8 + (v & 7)]
                                       : dp_num[(size_t)e * 2 + (v - 64)];
                    xbuf[sl][v] = x;
                }
                break;
            default:
                for (int v = q; v < 9; v += 8) {
                    float x = (v < 8) ? remit_tab[(size_t)remit_cat[e] * 8 + v]
                                      : remit_num[e];
                    xbuf[sl][v] = x;
                }
                break;
            }
        }
        __syncthreads();

        // ---- A1: per-column dot products -> window (2 events in flight) ----
        for (int sl = 0; sl < W0S; sl += 2) {
            const float accA = dot_evt(mcls[sl], xbuf[sl]);
            const float accB = dot_evt(mcls[sl + 1], xbuf[sl + 1]);
            window[sl * 256 + tid] = accA;
            window[(sl + 1) * 256 + tid] = accB;
        }
        __syncthreads();

        // ---- B: wave 0 runs W0S recurrence steps ----
        if (tid < 64) {
            float G[4], N[4];
#pragma unroll
            for (int k = 0; k < 4; ++k) G[k] = window[k * 64 + lane];
            for (int sl = 0; sl < W0S; ++sl) {
                const int slp = (sl + 1 < W0S) ? (sl + 1) : sl;   // clamp
#pragma unroll
                for (int k = 0; k < 4; ++k) N[k] = window[slp * 256 + k * 64 + lane];
                const float gi = fmaf(whh4[0], h, G[0]);
                const float gf = fmaf(whh4[1], h, G[1]);
                const float gg = fmaf(whh4[2], h, G[2]);
                const float go = fmaf(whh4[3], h, G[3]);
                c = sigm(gf) * c + sigm(gi) * tanh_f(gg);
                h = wave_sum_bcast(sigm(go) * tanh_f(c) * whr);
                const int s = s0 + sl;
                const int t = dir ? (TLEN - 1 - s) : s;
                if (lane == 0) h0p[(size_t)t * 2] = h;
#pragma unroll
                for (int k = 0; k < 4; ++k) G[k] = N[k];
            }
        }
        __syncthreads();   // protect xbuf/window before next phase overwrites
    }
}

// ===========================================================================
// LSTM layer 1 (insz=2), 2-step x prefetch. One wave per (b,dir). DPP reduce.
// ===========================================================================
__global__ __launch_bounds__(256) void lstm1_kernel(
    const float* __restrict__ h0, const float* __restrict__ Wih,
    const float* __restrict__ Whh, const float* __restrict__ Whr,
    const float* __restrict__ bih, const float* __restrict__ bhh,
    float* __restrict__ h1)
{
    int w = threadIdx.x >> 6, lane = threadIdx.x & 63;
    int p = blockIdx.x * 4 + w;
    int b = p >> 1, dir = p & 1;

    float wi0[4], wi1[4], whh[4], bias[4];
#pragma unroll
    for (int k = 0; k < 4; ++k) {
        int r = k * 64 + lane;
        wi0[k] = Wih[(size_t)(dir * 256 + r) * 2 + 0];
        wi1[k] = Wih[(size_t)(dir * 256 + r) * 2 + 1];
        whh[k] = Whh[dir * 256 + r];
        bias[k] = bih[dir * 256 + r] + bhh[dir * 256 + r];
    }
    float whr = Whr[dir * HID + lane];
    float h = 0.0f, c = 0.0f;
    const float* hb = h0 + (size_t)b * TLEN * 2;

    auto xat = [&](int t) -> float2 {
        int tc = t < TLEN ? t : TLEN - 1;
        int tt = dir ? (TLEN - 1 - tc) : tc;
        return *(const float2*)(hb + (size_t)tt * 2);
    };

    float2 xA = xat(0), xB = xat(1);
    for (int t = 0; t < TLEN; t += 2) {
        float2 xC = xat(t + 2), xD = xat(t + 3);
        {
            float g[4];
#pragma unroll
            for (int k = 0; k < 4; ++k)
                g[k] = fmaf(whh[k], h, fmaf(wi1[k], xA.y, fmaf(wi0[k], xA.x, bias[k])));
            c = sigm(g[1]) * c + sigm(g[0]) * tanh_f(g[2]);
            h = wave_sum_bcast(sigm(g[3]) * tanh_f(c) * whr);
            int tt = dir ? (TLEN - 1 - t) : t;
            if (lane == 0) h1[((size_t)b * TLEN + tt) * 2 + dir] = h;
        }
        {
            float g[4];
#pragma unroll
            for (int k = 0; k < 4; ++k)
                g[k] = fmaf(whh[k], h, fmaf(wi1[k], xB.y, fmaf(wi0[k], xB.x, bias[k])));
            c = sigm(g[1]) * c + sigm(g[0]) * tanh_f(g[2]);
            h = wave_sum_bcast(sigm(g[3]) * tanh_f(c) * whr);
            int tt = dir ? (TLEN - 2 - t) : (t + 1);
            if (lane == 0) h1[((size_t)b * TLEN + tt) * 2 + dir] = h;
        }
        xA = xC; xB = xD;
    }
}

__global__ __launch_bounds__(256) void mean_kernel(
    const float2* __restrict__ h1, float* __restrict__ out)
{
    int i = blockIdx.x * 256 + threadIdx.x;
    if (i < BATCH * TLEN) {
        float2 v = h1[i];
        out[i] = 0.5f * (v.x + v.y);
    }
}

// ===========================================================================
extern "C" void kernel_launch(void* const* d_in, const int* in_sizes, int n_in,
                              void* d_out, int out_size, void* d_ws, size_t ws_size,
                              hipStream_t stream)
{
    const float* ccba_num = (const float*)d_in[0];
    const int*   ccba_bi  = (const int*)d_in[1];
    const int*   ccba_ti  = (const int*)d_in[2];
    const float* ccba_W   = (const float*)d_in[3];
    const float* ccba_b   = (const float*)d_in[4];
    const float* cdtx_num = (const float*)d_in[5];
    const int*   cdtx_cat = (const int*)d_in[6];
    const float* cdtx_tab = (const float*)d_in[7];
    const int*   cdtx_bi  = (const int*)d_in[8];
    const int*   cdtx_ti  = (const int*)d_in[9];
    const float* cdtx_W   = (const float*)d_in[10];
    const float* cdtx_b   = (const float*)d_in[11];
    const float* cust_num = (const float*)d_in[12];
    const int*   cust_cat = (const int*)d_in[13];
    const float* cust_tab = (const float*)d_in[14];
    const int*   cust_bi  = (const int*)d_in[15];
    const int*   cust_ti  = (const int*)d_in[16];
    const float* cust_W   = (const float*)d_in[17];
    const float* cust_b   = (const float*)d_in[18];
    const float* dp_num   = (const float*)d_in[19];
    const int*   dp_cat   = (const int*)d_in[20];
    const float* dp_tab   = (const float*)d_in[21];
    const int*   dp_bi    = (const int*)d_in[22];
    const int*   dp_ti    = (const int*)d_in[23];
    const float* dp_W     = (const float*)d_in[24];
    const float* dp_b     = (const float*)d_in[25];
    const float* remit_num = (const float*)d_in[26];
    const int*   remit_cat = (const int*)d_in[27];
    const float* remit_tab = (const float*)d_in[28];
    const int*   remit_bi  = (const int*)d_in[29];
    const int*   remit_ti  = (const int*)d_in[30];
    const float* remit_W   = (const float*)d_in[31];
    const float* remit_b   = (const float*)d_in[32];
    const float* Wih0 = (const float*)d_in[33];
    const float* Whh0 = (const float*)d_in[34];
    const float* Whr0 = (const float*)d_in[35];
    const float* bih0 = (const float*)d_in[36];
    const float* bhh0 = (const float*)d_in[37];
    const float* Wih1 = (const float*)d_in[38];
    const float* Whh1 = (const float*)d_in[39];
    const float* Whr1 = (const float*)d_in[40];
    const float* bih1 = (const float*)d_in[41];
    const float* bhh1 = (const float*)d_in[42];

    float* out = (float*)d_out;

    // Workspace: wp (266,240) | map (2,048,000) | h0 (4,096,000) | h1 (4,096,000)
    char* ws = (char*)d_ws;
    float* wp  = (float*)ws;
    int*   map = (int*)  (ws + 266240ull);
    float* h0  = (float*)(ws + 266240ull + 2048000ull);
    float* h1  = (float*)(ws + 266240ull + 2048000ull + 4096000ull);

    compose_kernel<<<130, 512, 0, stream>>>(
        ccba_W, ccba_b, cdtx_W, cdtx_b, cust_W, cust_b,
        dp_W, dp_b, remit_W, remit_b, Wih0, bih0, bhh0, wp);

    map_build_kernel<<<dim3(NEVS / 256, 5), 256, 0, stream>>>(
        ccba_bi, ccba_ti, cdtx_bi, cdtx_ti, cust_bi, cust_ti,
        dp_bi, dp_ti, remit_bi, remit_ti, map);

    fused0_kernel<<<2 * BATCH, 256, 0, stream>>>(
        ccba_num,
        cdtx_num, cdtx_cat, cdtx_tab,
        cust_num, cust_cat, cust_tab,
        dp_num, dp_cat, dp_tab,
        remit_num, remit_cat, remit_tab,
        wp, map, Whh0, Whr0, h0);

    lstm1_kernel<<<500, 256, 0, stream>>>(h0, Wih1, Whh1, Whr1, bih1, bhh1, h1);
    mean_kernel<<<(BATCH * TLEN + 255) / 256, 256, 0, stream>>>((const float2*)h1, out);
}

// Round 4
// 1478.168 us; speedup vs baseline: 1.0983x; 1.0983x over previous
//
#include <hip/hip_runtime.h>
#include <cstdint>
#include <cstddef>

#define TLEN 512
#define BATCH 1000
#define NEVS 102400   // events per source
#define HID 64
#define W0S 16        // fused0 window steps per phase
#define NP (TLEN / W0S)

__device__ __forceinline__ float fast_rcp(float x) {
#if __has_builtin(__builtin_amdgcn_rcpf)
    return __builtin_amdgcn_rcpf(x);
#else
    return 1.0f / x;
#endif
}
__device__ __forceinline__ float sigm(float x) { return fast_rcp(1.0f + __expf(-x)); }
__device__ __forceinline__ float tanh_f(float x) { return fmaf(2.0f, sigm(2.0f * x), -1.0f); }

// Wave-wide sum broadcast (rocPRIM gfx9 DPP pattern).
__device__ __forceinline__ float wave_sum_bcast(float x) {
#if __has_builtin(__builtin_amdgcn_update_dpp) && __has_builtin(__builtin_amdgcn_readlane)
    x += __int_as_float(__builtin_amdgcn_update_dpp(0, __float_as_int(x), 0x111, 0xf, 0xf, true)); // row_shr:1
    x += __int_as_float(__builtin_amdgcn_update_dpp(0, __float_as_int(x), 0x112, 0xf, 0xf, true)); // row_shr:2
    x += __int_as_float(__builtin_amdgcn_update_dpp(0, __float_as_int(x), 0x114, 0xf, 0xf, true)); // row_shr:4
    x += __int_as_float(__builtin_amdgcn_update_dpp(0, __float_as_int(x), 0x118, 0xf, 0xf, true)); // row_shr:8
    x += __int_as_float(__builtin_amdgcn_update_dpp(0, __float_as_int(x), 0x142, 0xa, 0xf, true)); // row_bcast:15
    x += __int_as_float(__builtin_amdgcn_update_dpp(0, __float_as_int(x), 0x143, 0xc, 0xf, true)); // row_bcast:31
    return __int_as_float(__builtin_amdgcn_readlane(__float_as_int(x), 63));
#else
#pragma unroll
    for (int off = 1; off < 64; off <<= 1) x += __shfl_xor(x, off, 64);
    return x;
#endif
}

// Two independent wave sums, stages interleaved for ILP.
__device__ __forceinline__ void wave_sum2(float& a, float& b) {
#if __has_builtin(__builtin_amdgcn_update_dpp) && __has_builtin(__builtin_amdgcn_readlane)
    int ta, tb;
    ta = __builtin_amdgcn_update_dpp(0, __float_as_int(a), 0x111, 0xf, 0xf, true);
    tb = __builtin_amdgcn_update_dpp(0, __float_as_int(b), 0x111, 0xf, 0xf, true);
    a += __int_as_float(ta); b += __int_as_float(tb);
    ta = __builtin_amdgcn_update_dpp(0, __float_as_int(a), 0x112, 0xf, 0xf, true);
    tb = __builtin_amdgcn_update_dpp(0, __float_as_int(b), 0x112, 0xf, 0xf, true);
    a += __int_as_float(ta); b += __int_as_float(tb);
    ta = __builtin_amdgcn_update_dpp(0, __float_as_int(a), 0x114, 0xf, 0xf, true);
    tb = __builtin_amdgcn_update_dpp(0, __float_as_int(b), 0x114, 0xf, 0xf, true);
    a += __int_as_float(ta); b += __int_as_float(tb);
    ta = __builtin_amdgcn_update_dpp(0, __float_as_int(a), 0x118, 0xf, 0xf, true);
    tb = __builtin_amdgcn_update_dpp(0, __float_as_int(b), 0x118, 0xf, 0xf, true);
    a += __int_as_float(ta); b += __int_as_float(tb);
    ta = __builtin_amdgcn_update_dpp(0, __float_as_int(a), 0x142, 0xa, 0xf, true);
    tb = __builtin_amdgcn_update_dpp(0, __float_as_int(b), 0x142, 0xa, 0xf, true);
    a += __int_as_float(ta); b += __int_as_float(tb);
    ta = __builtin_amdgcn_update_dpp(0, __float_as_int(a), 0x143, 0xc, 0xf, true);
    tb = __builtin_amdgcn_update_dpp(0, __float_as_int(b), 0x143, 0xc, 0xf, true);
    a += __int_as_float(ta); b += __int_as_float(tb);
    a = __int_as_float(__builtin_amdgcn_readlane(__float_as_int(a), 63));
    b = __int_as_float(__builtin_amdgcn_readlane(__float_as_int(b), 63));
#else
    a = wave_sum_bcast(a); b = wave_sum_bcast(b);
#endif
}

// ===========================================================================
// map[b*512+t] = src<<20 | e  (sources partition the (b,t) grid: exactly one)
// ===========================================================================
__global__ __launch_bounds__(256) void map_build_kernel(
    const int* __restrict__ b0, const int* __restrict__ t0,
    const int* __restrict__ b1, const int* __restrict__ t1,
    const int* __restrict__ b2, const int* __restrict__ t2,
    const int* __restrict__ b3, const int* __restrict__ t3,
    const int* __restrict__ b4, const int* __restrict__ t4,
    int* __restrict__ map)
{
    const int src = blockIdx.y;
    const int* bi = src == 0 ? b0 : src == 1 ? b1 : src == 2 ? b2 : src == 3 ? b3 : b4;
    const int* ti = src == 0 ? t0 : src == 1 ? t1 : src == 2 ? t2 : src == 3 ? t3 : t4;
    const int e = blockIdx.x * 256 + threadIdx.x;
    map[bi[e] * TLEN + ti[e]] = (src << 20) | e;
}

// ===========================================================================
// Composed projection weights: wp[row][col], row=(src,j) [130], col=dir*256+r.
// row j<IND: W_src[j] . Wih0[col]; row j==IND: b_src . Wih0[col] + bih+bhh.
// ===========================================================================
__global__ __launch_bounds__(512) void compose_kernel(
    const float* __restrict__ W0, const float* __restrict__ B0,
    const float* __restrict__ W1, const float* __restrict__ B1,
    const float* __restrict__ W2, const float* __restrict__ B2,
    const float* __restrict__ W3, const float* __restrict__ B3,
    const float* __restrict__ W4, const float* __restrict__ B4,
    const float* __restrict__ Wih, const float* __restrict__ bih,
    const float* __restrict__ bhh, float* __restrict__ wp)
{
    const int col = threadIdx.x;   // 0..511 == dir*256 + r == Wih row index
    const int row = blockIdx.x;    // 0..129
    const float* srcW; const float* srcB; int base, IND;
    if (row < 9)        { srcW = W0; srcB = B0; base = 0;   IND = 8;  }
    else if (row < 27)  { srcW = W1; srcB = B1; base = 9;   IND = 17; }
    else if (row < 53)  { srcW = W2; srcB = B2; base = 27;  IND = 25; }
    else if (row < 120) { srcW = W3; srcB = B3; base = 53;  IND = 66; }
    else                { srcW = W4; srcB = B4; base = 120; IND = 9;  }
    const int j = row - base;
    const float* xrow = (j < IND) ? (srcW + (size_t)j * 64) : srcB;
    const float* wr = Wih + (size_t)col * 64;
    float acc = 0.0f;
#pragma unroll
    for (int h2 = 0; h2 < 64; ++h2) acc = fmaf(xrow[h2], wr[h2], acc);
    if (j == IND) acc += bih[col] + bhh[col];
    wp[(size_t)row * 512 + col] = acc;
}

// ===========================================================================
// Fused layer-0, v2.  Block = (b,dir), 512 threads (8 waves).
// Weight rows split across thread pairs: q = tid>>8 holds rows [0,h) (q=0)
// or [h,n) + bias (q=1) of every source -> max 66 regs/thread, guaranteed
// resident (two top-level template paths so the allocator sees one set).
// Per phase: A0 gathers next phase's x into xbuf (double-buffered, VMEM
// latency hides under A1); A1: 512 threads dot their q-half into partial
// windows; barrier; wave 0 runs W0S recurrence steps (adds partials);
// barrier.  Gates never touch global memory.
// ===========================================================================
template<bool HI>
__device__ __forceinline__ void fused_path(
    const float* __restrict__ wp, const int* __restrict__ map,
    const float* __restrict__ ccba_num,
    const float* __restrict__ cdtx_num, const int* __restrict__ cdtx_cat, const float* __restrict__ cdtx_tab,
    const float* __restrict__ cust_num, const int* __restrict__ cust_cat, const float* __restrict__ cust_tab,
    const float* __restrict__ dp_num,   const int* __restrict__ dp_cat,   const float* __restrict__ dp_tab,
    const float* __restrict__ remit_num, const int* __restrict__ remit_cat, const float* __restrict__ remit_tab,
    const float* __restrict__ Whh, const float* __restrict__ Whr,
    float* __restrict__ h0, int b, int dir, int tid,
    float (&winP)[2][W0S][256], float (&xbuf)[2][W0S][68], int (&mcls)[2][W0S])
{
    // FMA row counts / offsets per source for this half.
    constexpr int C0 = HI ? 3 : 5,  O0 = HI ? 5 : 0;    // ccba  (9 rows)
    constexpr int C1 = HI ? 8 : 9,  O1 = HI ? 9 : 0;    // cdtx  (18)
    constexpr int C2 = HI ? 12 : 13, O2 = HI ? 13 : 0;  // cust  (26)
    constexpr int C3 = HI ? 32 : 34, O3 = HI ? 34 : 0;  // dp    (67)
    constexpr int C4 = HI ? 4 : 5,  O4 = HI ? 5 : 0;    // remit (10)

    const int pcol = tid & 255;
    const int col = dir * 256 + pcol;

    float w0[C0], w1[C1], w2[C2], w3[C3], w4[C4];
#pragma unroll
    for (int j = 0; j < C0; ++j) w0[j] = wp[(size_t)(0 + O0 + j) * 512 + col];
#pragma unroll
    for (int j = 0; j < C1; ++j) w1[j] = wp[(size_t)(9 + O1 + j) * 512 + col];
#pragma unroll
    for (int j = 0; j < C2; ++j) w2[j] = wp[(size_t)(27 + O2 + j) * 512 + col];
#pragma unroll
    for (int j = 0; j < C3; ++j) w3[j] = wp[(size_t)(53 + O3 + j) * 512 + col];
#pragma unroll
    for (int j = 0; j < C4; ++j) w4[j] = wp[(size_t)(120 + O4 + j) * 512 + col];
    float bias0 = 0, bias1 = 0, bias2 = 0, bias3 = 0, bias4 = 0;
    if (HI) {
        bias0 = wp[(size_t)8 * 512 + col];
        bias1 = wp[(size_t)26 * 512 + col];
        bias2 = wp[(size_t)52 * 512 + col];
        bias3 = wp[(size_t)119 * 512 + col];
        bias4 = wp[(size_t)129 * 512 + col];
    }

    // Consumer state (only wave 0 of the q=0 path uses it).
    const int lane = tid & 63;
    float whh4[4] = {0, 0, 0, 0};
    float whr = 0.0f, h = 0.0f, c = 0.0f;
    if (!HI && tid < 64) {
#pragma unroll
        for (int k = 0; k < 4; ++k) whh4[k] = Whh[dir * 256 + k * 64 + lane];
        whr = Whr[dir * HID + lane];
    }
    float* h0p = h0 + (size_t)b * TLEN * 2 + dir;

    auto dot_evt = [&](int mc, const float* xb) -> float {
        const int src = mc >> 20;
        float a0 = 0.f, a1 = 0.f, bb = 0.f;
        switch (src) {
        case 0:
#pragma unroll
            for (int j = 0; j < C0; ++j) {
                if (j & 1) a1 = fmaf(xb[O0 + j], w0[j], a1); else a0 = fmaf(xb[O0 + j], w0[j], a0);
            }
            bb = bias0; break;
        case 1:
#pragma unroll
            for (int j = 0; j < C1; ++j) {
                if (j & 1) a1 = fmaf(xb[O1 + j], w1[j], a1); else a0 = fmaf(xb[O1 + j], w1[j], a0);
            }
            bb = bias1; break;
        case 2:
#pragma unroll
            for (int j = 0; j < C2; ++j) {
                if (j & 1) a1 = fmaf(xb[O2 + j], w2[j], a1); else a0 = fmaf(xb[O2 + j], w2[j], a0);
            }
            bb = bias2; break;
        case 3:
#pragma unroll
            for (int j = 0; j < C3; ++j) {
                if (j & 1) a1 = fmaf(xb[O3 + j], w3[j], a1); else a0 = fmaf(xb[O3 + j], w3[j], a0);
            }
            bb = bias3; break;
        default:
#pragma unroll
            for (int j = 0; j < C4; ++j) {
                if (j & 1) a1 = fmaf(xb[O4 + j], w4[j], a1); else a0 = fmaf(xb[O4 + j], w4[j], a0);
            }
            bb = bias4; break;
        }
        return HI ? (bb + a0 + a1) : (a0 + a1);
    };

    // A0: 32 threads per event gather its raw inputs into xbuf[slot].
    auto gather_phase = [&](int P, int slot) {
        const int ev = tid >> 5, v = tid & 31;   // 512 threads / 32 = 16 events
        const int s = P * W0S + ev;
        const int t = dir ? (TLEN - 1 - s) : s;
        const int mc = map[b * TLEN + t];
        if (v == 0) mcls[slot][ev] = mc;
        const int src = mc >> 20, e = mc & 0xFFFFF;
        switch (src) {
        case 0:
            if (v < 8) xbuf[slot][ev][v] = ccba_num[(size_t)e * 8 + v];
            break;
        case 1:
            if (v < 17) xbuf[slot][ev][v] = (v < 16)
                ? cdtx_tab[(size_t)cdtx_cat[e * 2 + (v >> 3)] * 8 + (v & 7)] : cdtx_num[e];
            break;
        case 2:
            if (v < 25) xbuf[slot][ev][v] = (v < 24)
                ? cust_tab[(size_t)cust_cat[e * 3 + (v >> 3)] * 8 + (v & 7)] : cust_num[e];
            break;
        case 3:
#pragma unroll
            for (int vv = v; vv < 66; vv += 32)
                xbuf[slot][ev][vv] = (vv < 64)
                    ? dp_tab[(size_t)dp_cat[e * 8 + (vv >> 3)] * 8 + (vv & 7)]
                    : dp_num[(size_t)e * 2 + (vv - 64)];
            break;
        default:
            if (v < 9) xbuf[slot][ev][v] = (v < 8)
                ? remit_tab[(size_t)remit_cat[e] * 8 + v] : remit_num[e];
            break;
        }
    };

    // A1: dot this phase's events against the resident half-rows.
    auto dots_phase = [&](int slot) {
#pragma unroll 1
        for (int sl = 0; sl < W0S; sl += 2) {
            const int mc0 = mcls[slot][sl];
            const int mc1 = mcls[slot][sl + 1];
            const float a = dot_evt(mc0, xbuf[slot][sl]);
            const float bq = dot_evt(mc1, xbuf[slot][sl + 1]);
            winP[HI ? 1 : 0][sl][pcol] = a;
            winP[HI ? 1 : 0][sl + 1][pcol] = bq;
        }
    };

    gather_phase(0, 0);
    __syncthreads();

    for (int p = 0; p < NP; ++p) {
        if (p + 1 < NP) gather_phase(p + 1, (p + 1) & 1);   // VMEM in flight under A1
        dots_phase(p & 1);
        __syncthreads();

        if (!HI && tid < 64) {
            float G0[4], G1[4];
#pragma unroll
            for (int k = 0; k < 4; ++k) {
                G0[k] = winP[0][0][k * 64 + lane];
                G1[k] = winP[1][0][k * 64 + lane];
            }
            for (int sl = 0; sl < W0S; ++sl) {
                const int sn = (sl + 1 < W0S) ? sl + 1 : sl;
                float N0[4], N1[4];
#pragma unroll
                for (int k = 0; k < 4; ++k) {
                    N0[k] = winP[0][sn][k * 64 + lane];
                    N1[k] = winP[1][sn][k * 64 + lane];
                }
                const float gi = fmaf(whh4[0], h, G0[0] + G1[0]);
                const float gf = fmaf(whh4[1], h, G0[1] + G1[1]);
                const float gg = fmaf(whh4[2], h, G0[2] + G1[2]);
                const float go = fmaf(whh4[3], h, G0[3] + G1[3]);
                c = sigm(gf) * c + sigm(gi) * tanh_f(gg);
                h = wave_sum_bcast(sigm(go) * tanh_f(c) * whr);
                const int s = p * W0S + sl;
                const int t = dir ? (TLEN - 1 - s) : s;
                if (lane == 0) h0p[(size_t)t * 2] = h;
#pragma unroll
                for (int k = 0; k < 4; ++k) { G0[k] = N0[k]; G1[k] = N1[k]; }
            }
        }
        __syncthreads();
    }
}

__global__ __launch_bounds__(512, 4) void fused0_kernel(
    const float* __restrict__ ccba_num,
    const float* __restrict__ cdtx_num, const int* __restrict__ cdtx_cat, const float* __restrict__ cdtx_tab,
    const float* __restrict__ cust_num, const int* __restrict__ cust_cat, const float* __restrict__ cust_tab,
    const float* __restrict__ dp_num,   const int* __restrict__ dp_cat,   const float* __restrict__ dp_tab,
    const float* __restrict__ remit_num, const int* __restrict__ remit_cat, const float* __restrict__ remit_tab,
    const float* __restrict__ wp, const int* __restrict__ map,
    const float* __restrict__ Whh, const float* __restrict__ Whr,
    float* __restrict__ h0)
{
    __shared__ float winP[2][W0S][256];
    __shared__ float xbuf[2][W0S][68];
    __shared__ int   mcls[2][W0S];
    const int tid = threadIdx.x;
    const int b = blockIdx.x >> 1, dir = blockIdx.x & 1;
    if (tid < 256)
        fused_path<false>(wp, map, ccba_num,
            cdtx_num, cdtx_cat, cdtx_tab, cust_num, cust_cat, cust_tab,
            dp_num, dp_cat, dp_tab, remit_num, remit_cat, remit_tab,
            Whh, Whr, h0, b, dir, tid, winP, xbuf, mcls);
    else
        fused_path<true>(wp, map, ccba_num,
            cdtx_num, cdtx_cat, cdtx_tab, cust_num, cust_cat, cust_tab,
            dp_num, dp_cat, dp_tab, remit_num, remit_cat, remit_tab,
            Whh, Whr, h0, b, dir, tid, winP, xbuf, mcls);
}

// ===========================================================================
// LSTM layer 1 (insz=2): one wave per b, BOTH dirs as two interleaved chains
// (independent serial chains -> 2x latency hiding). DPP paired reduce.
// ===========================================================================
__global__ __launch_bounds__(256) void lstm1_kernel(
    const float* __restrict__ h0, const float* __restrict__ Wih,
    const float* __restrict__ Whh, const float* __restrict__ Whr,
    const float* __restrict__ bih, const float* __restrict__ bhh,
    float* __restrict__ h1)
{
    const int w = threadIdx.x >> 6, lane = threadIdx.x & 63;
    const int b = blockIdx.x * 4 + w;              // grid 250 -> b 0..999

    float wi0[2][4], wi1[2][4], whh[2][4], bias[2][4], whr[2];
#pragma unroll
    for (int d = 0; d < 2; ++d) {
#pragma unroll
        for (int k = 0; k < 4; ++k) {
            const int r = d * 256 + k * 64 + lane;
            wi0[d][k] = Wih[(size_t)r * 2 + 0];
            wi1[d][k] = Wih[(size_t)r * 2 + 1];
            whh[d][k] = Whh[r];
            bias[d][k] = bih[r] + bhh[r];
        }
        whr[d] = Whr[d * HID + lane];
    }
    float hA = 0, cA = 0, hB = 0, cB = 0;
    const float* hb = h0 + (size_t)b * TLEN * 2;

    float2 xA = *(const float2*)(hb);                         // fwd t=0
    float2 xB = *(const float2*)(hb + (size_t)(TLEN - 1) * 2); // bwd t=511
    for (int t = 0; t < TLEN; ++t) {
        const int tn = (t + 1 < TLEN) ? t + 1 : t;
        const float2 xAn = *(const float2*)(hb + (size_t)tn * 2);
        const float2 xBn = *(const float2*)(hb + (size_t)(TLEN - 1 - tn) * 2);
        float gA[4], gB[4];
#pragma unroll
        for (int k = 0; k < 4; ++k) {
            gA[k] = fmaf(whh[0][k], hA, fmaf(wi1[0][k], xA.y, fmaf(wi0[0][k], xA.x, bias[0][k])));
            gB[k] = fmaf(whh[1][k], hB, fmaf(wi1[1][k], xB.y, fmaf(wi0[1][k], xB.x, bias[1][k])));
        }
        cA = sigm(gA[1]) * cA + sigm(gA[0]) * tanh_f(gA[2]);
        cB = sigm(gB[1]) * cB + sigm(gB[0]) * tanh_f(gB[2]);
        float pA = sigm(gA[3]) * tanh_f(cA) * whr[0];
        float pB = sigm(gB[3]) * tanh_f(cB) * whr[1];
        wave_sum2(pA, pB);
        hA = pA; hB = pB;
        if (lane == 0) {
            h1[((size_t)b * TLEN + t) * 2 + 0] = hA;
            h1[((size_t)b * TLEN + (TLEN - 1 - t)) * 2 + 1] = hB;
        }
        xA = xAn; xB = xBn;
    }
}

__global__ __launch_bounds__(256) void mean_kernel(
    const float2* __restrict__ h1, float* __restrict__ out)
{
    int i = blockIdx.x * 256 + threadIdx.x;
    if (i < BATCH * TLEN) {
        float2 v = h1[i];
        out[i] = 0.5f * (v.x + v.y);
    }
}

// ===========================================================================
extern "C" void kernel_launch(void* const* d_in, const int* in_sizes, int n_in,
                              void* d_out, int out_size, void* d_ws, size_t ws_size,
                              hipStream_t stream)
{
    const float* ccba_num = (const float*)d_in[0];
    const int*   ccba_bi  = (const int*)d_in[1];
    const int*   ccba_ti  = (const int*)d_in[2];
    const float* ccba_W   = (const float*)d_in[3];
    const float* ccba_b   = (const float*)d_in[4];
    const float* cdtx_num = (const float*)d_in[5];
    const int*   cdtx_cat = (const int*)d_in[6];
    const float* cdtx_tab = (const float*)d_in[7];
    const int*   cdtx_bi  = (const int*)d_in[8];
    const int*   cdtx_ti  = (const int*)d_in[9];
    const float* cdtx_W   = (const float*)d_in[10];
    const float* cdtx_b   = (const float*)d_in[11];
    const float* cust_num = (const float*)d_in[12];
    const int*   cust_cat = (const int*)d_in[13];
    const float* cust_tab = (const float*)d_in[14];
    const int*   cust_bi  = (const int*)d_in[15];
    const int*   cust_ti  = (const int*)d_in[16];
    const float* cust_W   = (const float*)d_in[17];
    const float* cust_b   = (const float*)d_in[18];
    const float* dp_num   = (const float*)d_in[19];
    const int*   dp_cat   = (const int*)d_in[20];
    const float* dp_tab   = (const float*)d_in[21];
    const int*   dp_bi    = (const int*)d_in[22];
    const int*   dp_ti    = (const int*)d_in[23];
    const float* dp_W     = (const float*)d_in[24];
    const float* dp_b     = (const float*)d_in[25];
    const float* remit_num = (const float*)d_in[26];
    const int*   remit_cat = (const int*)d_in[27];
    const float* remit_tab = (const float*)d_in[28];
    const int*   remit_bi  = (const int*)d_in[29];
    const int*   remit_ti  = (const int*)d_in[30];
    const float* remit_W   = (const float*)d_in[31];
    const float* remit_b   = (const float*)d_in[32];
    const float* Wih0 = (const float*)d_in[33];
    const float* Whh0 = (const float*)d_in[34];
    const float* Whr0 = (const float*)d_in[35];
    const float* bih0 = (const float*)d_in[36];
    const float* bhh0 = (const float*)d_in[37];
    const float* Wih1 = (const float*)d_in[38];
    const float* Whh1 = (const float*)d_in[39];
    const float* Whr1 = (const float*)d_in[40];
    const float* bih1 = (const float*)d_in[41];
    const float* bhh1 = (const float*)d_in[42];

    float* out = (float*)d_out;

    // Workspace: wp (266,240) | map (2,048,000) | h0 (4,096,000) | h1 (4,096,000)
    char* ws = (char*)d_ws;
    float* wp  = (float*)ws;
    int*   map = (int*)  (ws + 266240ull);
    float* h0  = (float*)(ws + 266240ull + 2048000ull);
    float* h1  = (float*)(ws + 266240ull + 2048000ull + 4096000ull);

    compose_kernel<<<130, 512, 0, stream>>>(
        ccba_W, ccba_b, cdtx_W, cdtx_b, cust_W, cust_b,
        dp_W, dp_b, remit_W, remit_b, Wih0, bih0, bhh0, wp);

    map_build_kernel<<<dim3(NEVS / 256, 5), 256, 0, stream>>>(
        ccba_bi, ccba_ti, cdtx_bi, cdtx_ti, cust_bi, cust_ti,
        dp_bi, dp_ti, remit_bi, remit_ti, map);

    fused0_kernel<<<2 * BATCH, 512, 0, stream>>>(
        ccba_num,
        cdtx_num, cdtx_cat, cdtx_tab,
        cust_num, cust_cat, cust_tab,
        dp_num, dp_cat, dp_tab,
        remit_num, remit_cat, remit_tab,
        wp, map, Whh0, Whr0, h0);

    lstm1_kernel<<<250, 256, 0, stream>>>(h0, Wih1, Whh1, Whr1, bih1, bhh1, h1);
    mean_kernel<<<(BATCH * TLEN + 255) / 256, 256, 0, stream>>>((const float2*)h1, out);
}

// Round 5
// 1465.412 us; speedup vs baseline: 1.1079x; 1.0087x over previous
//
#include <hip/hip_runtime.h>
#include <cstdint>
#include <cstddef>

#define TLEN 512
#define BATCH 1000
#define NEVS 102400   // events per source
#define HID 64
#define W0S 16        // fused0 window steps per phase
#define NP (TLEN / W0S)

__device__ __forceinline__ float fast_rcp(float x) {
#if __has_builtin(__builtin_amdgcn_rcpf)
    return __builtin_amdgcn_rcpf(x);
#else
    return 1.0f / x;
#endif
}
__device__ __forceinline__ float sigm(float x) { return fast_rcp(1.0f + __expf(-x)); }
__device__ __forceinline__ float tanh_f(float x) { return fmaf(2.0f, sigm(2.0f * x), -1.0f); }

// Opaque pin: value becomes asm-defined -> compiler cannot sink/remat the load.
__device__ __forceinline__ void pin(float& x) { asm volatile("" : "+v"(x)); }

// Wave-wide sum broadcast (rocPRIM gfx9 DPP pattern).
__device__ __forceinline__ float wave_sum_bcast(float x) {
#if __has_builtin(__builtin_amdgcn_update_dpp) && __has_builtin(__builtin_amdgcn_readlane)
    x += __int_as_float(__builtin_amdgcn_update_dpp(0, __float_as_int(x), 0x111, 0xf, 0xf, true)); // row_shr:1
    x += __int_as_float(__builtin_amdgcn_update_dpp(0, __float_as_int(x), 0x112, 0xf, 0xf, true)); // row_shr:2
    x += __int_as_float(__builtin_amdgcn_update_dpp(0, __float_as_int(x), 0x114, 0xf, 0xf, true)); // row_shr:4
    x += __int_as_float(__builtin_amdgcn_update_dpp(0, __float_as_int(x), 0x118, 0xf, 0xf, true)); // row_shr:8
    x += __int_as_float(__builtin_amdgcn_update_dpp(0, __float_as_int(x), 0x142, 0xa, 0xf, true)); // row_bcast:15
    x += __int_as_float(__builtin_amdgcn_update_dpp(0, __float_as_int(x), 0x143, 0xc, 0xf, true)); // row_bcast:31
    return __int_as_float(__builtin_amdgcn_readlane(__float_as_int(x), 63));
#else
#pragma unroll
    for (int off = 1; off < 64; off <<= 1) x += __shfl_xor(x, off, 64);
    return x;
#endif
}

// Two independent wave sums, stages interleaved for ILP.
__device__ __forceinline__ void wave_sum2(float& a, float& b) {
#if __has_builtin(__builtin_amdgcn_update_dpp) && __has_builtin(__builtin_amdgcn_readlane)
    int ta, tb;
    ta = __builtin_amdgcn_update_dpp(0, __float_as_int(a), 0x111, 0xf, 0xf, true);
    tb = __builtin_amdgcn_update_dpp(0, __float_as_int(b), 0x111, 0xf, 0xf, true);
    a += __int_as_float(ta); b += __int_as_float(tb);
    ta = __builtin_amdgcn_update_dpp(0, __float_as_int(a), 0x112, 0xf, 0xf, true);
    tb = __builtin_amdgcn_update_dpp(0, __float_as_int(b), 0x112, 0xf, 0xf, true);
    a += __int_as_float(ta); b += __int_as_float(tb);
    ta = __builtin_amdgcn_update_dpp(0, __float_as_int(a), 0x114, 0xf, 0xf, true);
    tb = __builtin_amdgcn_update_dpp(0, __float_as_int(b), 0x114, 0xf, 0xf, true);
    a += __int_as_float(ta); b += __int_as_float(tb);
    ta = __builtin_amdgcn_update_dpp(0, __float_as_int(a), 0x118, 0xf, 0xf, true);
    tb = __builtin_amdgcn_update_dpp(0, __float_as_int(b), 0x118, 0xf, 0xf, true);
    a += __int_as_float(ta); b += __int_as_float(tb);
    ta = __builtin_amdgcn_update_dpp(0, __float_as_int(a), 0x142, 0xa, 0xf, true);
    tb = __builtin_amdgcn_update_dpp(0, __float_as_int(b), 0x142, 0xa, 0xf, true);
    a += __int_as_float(ta); b += __int_as_float(tb);
    ta = __builtin_amdgcn_update_dpp(0, __float_as_int(a), 0x143, 0xc, 0xf, true);
    tb = __builtin_amdgcn_update_dpp(0, __float_as_int(b), 0x143, 0xc, 0xf, true);
    a += __int_as_float(ta); b += __int_as_float(tb);
    a = __int_as_float(__builtin_amdgcn_readlane(__float_as_int(a), 63));
    b = __int_as_float(__builtin_amdgcn_readlane(__float_as_int(b), 63));
#else
    a = wave_sum_bcast(a); b = wave_sum_bcast(b);
#endif
}

// ===========================================================================
// map[b*512+t] = src<<20 | e  (sources partition the (b,t) grid: exactly one)
// ===========================================================================
__global__ __launch_bounds__(256) void map_build_kernel(
    const int* __restrict__ b0, const int* __restrict__ t0,
    const int* __restrict__ b1, const int* __restrict__ t1,
    const int* __restrict__ b2, const int* __restrict__ t2,
    const int* __restrict__ b3, const int* __restrict__ t3,
    const int* __restrict__ b4, const int* __restrict__ t4,
    int* __restrict__ map)
{
    const int src = blockIdx.y;
    const int* bi = src == 0 ? b0 : src == 1 ? b1 : src == 2 ? b2 : src == 3 ? b3 : b4;
    const int* ti = src == 0 ? t0 : src == 1 ? t1 : src == 2 ? t2 : src == 3 ? t3 : t4;
    const int e = blockIdx.x * 256 + threadIdx.x;
    map[bi[e] * TLEN + ti[e]] = (src << 20) | e;
}

// ===========================================================================
// Composed projection weights: wp[row][col], row=(src,j) [130], col=dir*256+r.
// row j<IND: W_src[j] . Wih0[col]; row j==IND: b_src . Wih0[col] + bih+bhh.
// ===========================================================================
__global__ __launch_bounds__(512) void compose_kernel(
    const float* __restrict__ W0, const float* __restrict__ B0,
    const float* __restrict__ W1, const float* __restrict__ B1,
    const float* __restrict__ W2, const float* __restrict__ B2,
    const float* __restrict__ W3, const float* __restrict__ B3,
    const float* __restrict__ W4, const float* __restrict__ B4,
    const float* __restrict__ Wih, const float* __restrict__ bih,
    const float* __restrict__ bhh, float* __restrict__ wp)
{
    const int col = threadIdx.x;   // 0..511 == dir*256 + r == Wih row index
    const int row = blockIdx.x;    // 0..129
    const float* srcW; const float* srcB; int base, IND;
    if (row < 9)        { srcW = W0; srcB = B0; base = 0;   IND = 8;  }
    else if (row < 27)  { srcW = W1; srcB = B1; base = 9;   IND = 17; }
    else if (row < 53)  { srcW = W2; srcB = B2; base = 27;  IND = 25; }
    else if (row < 120) { srcW = W3; srcB = B3; base = 53;  IND = 66; }
    else                { srcW = W4; srcB = B4; base = 120; IND = 9;  }
    const int j = row - base;
    const float* xrow = (j < IND) ? (srcW + (size_t)j * 64) : srcB;
    const float* wr = Wih + (size_t)col * 64;
    float acc = 0.0f;
#pragma unroll
    for (int h2 = 0; h2 < 64; ++h2) acc = fmaf(xrow[h2], wr[h2], acc);
    if (j == IND) acc += bih[col] + bhh[col];
    wp[(size_t)row * 512 + col] = acc;
}

// ===========================================================================
// Fused layer-0, v3 = v2 + pinned weight registers.
// Block = (b,dir), 512 threads (8 waves); q = tid>>8 selects row-half.
// ===========================================================================
template<bool HI>
__device__ __forceinline__ void fused_path(
    const float* __restrict__ wp, const int* __restrict__ map,
    const float* __restrict__ ccba_num,
    const float* __restrict__ cdtx_num, const int* __restrict__ cdtx_cat, const float* __restrict__ cdtx_tab,
    const float* __restrict__ cust_num, const int* __restrict__ cust_cat, const float* __restrict__ cust_tab,
    const float* __restrict__ dp_num,   const int* __restrict__ dp_cat,   const float* __restrict__ dp_tab,
    const float* __restrict__ remit_num, const int* __restrict__ remit_cat, const float* __restrict__ remit_tab,
    const float* __restrict__ Whh, const float* __restrict__ Whr,
    float* __restrict__ h0, int b, int dir, int tid,
    float (&winP)[2][W0S][256], float (&xbuf)[2][W0S][68], int (&mcls)[2][W0S])
{
    // FMA row counts / offsets per source for this half.
    constexpr int C0 = HI ? 3 : 5,  O0 = HI ? 5 : 0;    // ccba  (9 rows)
    constexpr int C1 = HI ? 8 : 9,  O1 = HI ? 9 : 0;    // cdtx  (18)
    constexpr int C2 = HI ? 12 : 13, O2 = HI ? 13 : 0;  // cust  (26)
    constexpr int C3 = HI ? 32 : 34, O3 = HI ? 34 : 0;  // dp    (67)
    constexpr int C4 = HI ? 4 : 5,  O4 = HI ? 5 : 0;    // remit (10)

    const int pcol = tid & 255;
    const int col = dir * 256 + pcol;

    float w0[C0], w1[C1], w2[C2], w3[C3], w4[C4];
#pragma unroll
    for (int j = 0; j < C0; ++j) w0[j] = wp[(size_t)(0 + O0 + j) * 512 + col];
#pragma unroll
    for (int j = 0; j < C1; ++j) w1[j] = wp[(size_t)(9 + O1 + j) * 512 + col];
#pragma unroll
    for (int j = 0; j < C2; ++j) w2[j] = wp[(size_t)(27 + O2 + j) * 512 + col];
#pragma unroll
    for (int j = 0; j < C3; ++j) w3[j] = wp[(size_t)(53 + O3 + j) * 512 + col];
#pragma unroll
    for (int j = 0; j < C4; ++j) w4[j] = wp[(size_t)(120 + O4 + j) * 512 + col];
    float bias0 = 0, bias1 = 0, bias2 = 0, bias3 = 0, bias4 = 0;
    if (HI) {
        bias0 = wp[(size_t)8 * 512 + col];
        bias1 = wp[(size_t)26 * 512 + col];
        bias2 = wp[(size_t)52 * 512 + col];
        bias3 = wp[(size_t)119 * 512 + col];
        bias4 = wp[(size_t)129 * 512 + col];
    }
    // Pin every weight into a VGPR: loads can't be sunk/rematerialized into
    // the per-event loop (round-4 post-mortem: VGPR=60, 27 GB L2 re-fetch).
#pragma unroll
    for (int j = 0; j < C0; ++j) pin(w0[j]);
#pragma unroll
    for (int j = 0; j < C1; ++j) pin(w1[j]);
#pragma unroll
    for (int j = 0; j < C2; ++j) pin(w2[j]);
#pragma unroll
    for (int j = 0; j < C3; ++j) pin(w3[j]);
#pragma unroll
    for (int j = 0; j < C4; ++j) pin(w4[j]);
    if (HI) { pin(bias0); pin(bias1); pin(bias2); pin(bias3); pin(bias4); }

    // Consumer state (only wave 0 of the q=0 path uses it).
    const int lane = tid & 63;
    float whh4[4] = {0, 0, 0, 0};
    float whr = 0.0f, h = 0.0f, c = 0.0f;
    if (!HI && tid < 64) {
#pragma unroll
        for (int k = 0; k < 4; ++k) whh4[k] = Whh[dir * 256 + k * 64 + lane];
        whr = Whr[dir * HID + lane];
    }
    float* h0p = h0 + (size_t)b * TLEN * 2 + dir;

    auto dot_evt = [&](int mc, const float* xb) -> float {
        const int src = mc >> 20;
        float a0 = 0.f, a1 = 0.f, bb = 0.f;
        switch (src) {
        case 0:
#pragma unroll
            for (int j = 0; j < C0; ++j) {
                if (j & 1) a1 = fmaf(xb[O0 + j], w0[j], a1); else a0 = fmaf(xb[O0 + j], w0[j], a0);
            }
            bb = bias0; break;
        case 1:
#pragma unroll
            for (int j = 0; j < C1; ++j) {
                if (j & 1) a1 = fmaf(xb[O1 + j], w1[j], a1); else a0 = fmaf(xb[O1 + j], w1[j], a0);
            }
            bb = bias1; break;
        case 2:
#pragma unroll
            for (int j = 0; j < C2; ++j) {
                if (j & 1) a1 = fmaf(xb[O2 + j], w2[j], a1); else a0 = fmaf(xb[O2 + j], w2[j], a0);
            }
            bb = bias2; break;
        case 3:
#pragma unroll
            for (int j = 0; j < C3; ++j) {
                if (j & 1) a1 = fmaf(xb[O3 + j], w3[j], a1); else a0 = fmaf(xb[O3 + j], w3[j], a0);
            }
            bb = bias3; break;
        default:
#pragma unroll
            for (int j = 0; j < C4; ++j) {
                if (j & 1) a1 = fmaf(xb[O4 + j], w4[j], a1); else a0 = fmaf(xb[O4 + j], w4[j], a0);
            }
            bb = bias4; break;
        }
        return HI ? (bb + a0 + a1) : (a0 + a1);
    };

    // A0: 32 threads per event gather its raw inputs into xbuf[slot].
    auto gather_phase = [&](int P, int slot) {
        const int ev = tid >> 5, v = tid & 31;   // 512 threads / 32 = 16 events
        const int s = P * W0S + ev;
        const int t = dir ? (TLEN - 1 - s) : s;
        const int mc = map[b * TLEN + t];
        if (v == 0) mcls[slot][ev] = mc;
        const int src = mc >> 20, e = mc & 0xFFFFF;
        switch (src) {
        case 0:
            if (v < 8) xbuf[slot][ev][v] = ccba_num[(size_t)e * 8 + v];
            break;
        case 1:
            if (v < 17) xbuf[slot][ev][v] = (v < 16)
                ? cdtx_tab[(size_t)cdtx_cat[e * 2 + (v >> 3)] * 8 + (v & 7)] : cdtx_num[e];
            break;
        case 2:
            if (v < 25) xbuf[slot][ev][v] = (v < 24)
                ? cust_tab[(size_t)cust_cat[e * 3 + (v >> 3)] * 8 + (v & 7)] : cust_num[e];
            break;
        case 3:
#pragma unroll
            for (int vv = v; vv < 66; vv += 32)
                xbuf[slot][ev][vv] = (vv < 64)
                    ? dp_tab[(size_t)dp_cat[e * 8 + (vv >> 3)] * 8 + (vv & 7)]
                    : dp_num[(size_t)e * 2 + (vv - 64)];
            break;
        default:
            if (v < 9) xbuf[slot][ev][v] = (v < 8)
                ? remit_tab[(size_t)remit_cat[e] * 8 + v] : remit_num[e];
            break;
        }
    };

    // A1: dot this phase's events against the resident half-rows.
    auto dots_phase = [&](int slot) {
#pragma unroll 1
        for (int sl = 0; sl < W0S; sl += 2) {
            const int mc0 = mcls[slot][sl];
            const int mc1 = mcls[slot][sl + 1];
            const float a = dot_evt(mc0, xbuf[slot][sl]);
            const float bq = dot_evt(mc1, xbuf[slot][sl + 1]);
            winP[HI ? 1 : 0][sl][pcol] = a;
            winP[HI ? 1 : 0][sl + 1][pcol] = bq;
        }
    };

    gather_phase(0, 0);
    __syncthreads();

    for (int p = 0; p < NP; ++p) {
        if (p + 1 < NP) gather_phase(p + 1, (p + 1) & 1);   // VMEM in flight under A1
        dots_phase(p & 1);
        __syncthreads();

        if (!HI && tid < 64) {
            float G0[4], G1[4];
#pragma unroll
            for (int k = 0; k < 4; ++k) {
                G0[k] = winP[0][0][k * 64 + lane];
                G1[k] = winP[1][0][k * 64 + lane];
            }
            for (int sl = 0; sl < W0S; ++sl) {
                const int sn = (sl + 1 < W0S) ? sl + 1 : sl;
                float N0[4], N1[4];
#pragma unroll
                for (int k = 0; k < 4; ++k) {
                    N0[k] = winP[0][sn][k * 64 + lane];
                    N1[k] = winP[1][sn][k * 64 + lane];
                }
                const float gi = fmaf(whh4[0], h, G0[0] + G1[0]);
                const float gf = fmaf(whh4[1], h, G0[1] + G1[1]);
                const float gg = fmaf(whh4[2], h, G0[2] + G1[2]);
                const float go = fmaf(whh4[3], h, G0[3] + G1[3]);
                c = sigm(gf) * c + sigm(gi) * tanh_f(gg);
                h = wave_sum_bcast(sigm(go) * tanh_f(c) * whr);
                const int s = p * W0S + sl;
                const int t = dir ? (TLEN - 1 - s) : s;
                if (lane == 0) h0p[(size_t)t * 2] = h;
#pragma unroll
                for (int k = 0; k < 4; ++k) { G0[k] = N0[k]; G1[k] = N1[k]; }
            }
        }
        __syncthreads();
    }
}

__global__ __launch_bounds__(512, 4) void fused0_kernel(
    const float* __restrict__ ccba_num,
    const float* __restrict__ cdtx_num, const int* __restrict__ cdtx_cat, const float* __restrict__ cdtx_tab,
    const float* __restrict__ cust_num, const int* __restrict__ cust_cat, const float* __restrict__ cust_tab,
    const float* __restrict__ dp_num,   const int* __restrict__ dp_cat,   const float* __restrict__ dp_tab,
    const float* __restrict__ remit_num, const int* __restrict__ remit_cat, const float* __restrict__ remit_tab,
    const float* __restrict__ wp, const int* __restrict__ map,
    const float* __restrict__ Whh, const float* __restrict__ Whr,
    float* __restrict__ h0)
{
    __shared__ float winP[2][W0S][256];
    __shared__ float xbuf[2][W0S][68];
    __shared__ int   mcls[2][W0S];
    const int tid = threadIdx.x;
    const int b = blockIdx.x >> 1, dir = blockIdx.x & 1;
    if (tid < 256)
        fused_path<false>(wp, map, ccba_num,
            cdtx_num, cdtx_cat, cdtx_tab, cust_num, cust_cat, cust_tab,
            dp_num, dp_cat, dp_tab, remit_num, remit_cat, remit_tab,
            Whh, Whr, h0, b, dir, tid, winP, xbuf, mcls);
    else
        fused_path<true>(wp, map, ccba_num,
            cdtx_num, cdtx_cat, cdtx_tab, cust_num, cust_cat, cust_tab,
            dp_num, dp_cat, dp_tab, remit_num, remit_cat, remit_tab,
            Whh, Whr, h0, b, dir, tid, winP, xbuf, mcls);
}

// ===========================================================================
// LSTM layer 1 (insz=2): one wave per b, BOTH dirs as two interleaved chains
// (independent serial chains -> 2x latency hiding). DPP paired reduce.
// Weights pinned (serial chain cannot hide re-load latency).
// ===========================================================================
__global__ __launch_bounds__(256) void lstm1_kernel(
    const float* __restrict__ h0, const float* __restrict__ Wih,
    const float* __restrict__ Whh, const float* __restrict__ Whr,
    const float* __restrict__ bih, const float* __restrict__ bhh,
    float* __restrict__ h1)
{
    const int w = threadIdx.x >> 6, lane = threadIdx.x & 63;
    const int b = blockIdx.x * 4 + w;              // grid 250 -> b 0..999

    float wi0[2][4], wi1[2][4], whh[2][4], bias[2][4], whr[2];
#pragma unroll
    for (int d = 0; d < 2; ++d) {
#pragma unroll
        for (int k = 0; k < 4; ++k) {
            const int r = d * 256 + k * 64 + lane;
            wi0[d][k] = Wih[(size_t)r * 2 + 0];
            wi1[d][k] = Wih[(size_t)r * 2 + 1];
            whh[d][k] = Whh[r];
            bias[d][k] = bih[r] + bhh[r];
        }
        whr[d] = Whr[d * HID + lane];
    }
#pragma unroll
    for (int d = 0; d < 2; ++d) {
#pragma unroll
        for (int k = 0; k < 4; ++k) { pin(wi0[d][k]); pin(wi1[d][k]); pin(whh[d][k]); pin(bias[d][k]); }
        pin(whr[d]);
    }
    float hA = 0, cA = 0, hB = 0, cB = 0;
    const float* hb = h0 + (size_t)b * TLEN * 2;

    float2 xA = *(const float2*)(hb);                          // fwd t=0
    float2 xB = *(const float2*)(hb + (size_t)(TLEN - 1) * 2); // bwd t=511
    for (int t = 0; t < TLEN; ++t) {
        const int tn = (t + 1 < TLEN) ? t + 1 : t;
        const float2 xAn = *(const float2*)(hb + (size_t)tn * 2);
        const float2 xBn = *(const float2*)(hb + (size_t)(TLEN - 1 - tn) * 2);
        float gA[4], gB[4];
#pragma unroll
        for (int k = 0; k < 4; ++k) {
            gA[k] = fmaf(whh[0][k], hA, fmaf(wi1[0][k], xA.y, fmaf(wi0[0][k], xA.x, bias[0][k])));
            gB[k] = fmaf(whh[1][k], hB, fmaf(wi1[1][k], xB.y, fmaf(wi0[1][k], xB.x, bias[1][k])));
        }
        cA = sigm(gA[1]) * cA + sigm(gA[0]) * tanh_f(gA[2]);
        cB = sigm(gB[1]) * cB + sigm(gB[0]) * tanh_f(gB[2]);
        float pA = sigm(gA[3]) * tanh_f(cA) * whr[0];
        float pB = sigm(gB[3]) * tanh_f(cB) * whr[1];
        wave_sum2(pA, pB);
        hA = pA; hB = pB;
        if (lane == 0) {
            h1[((size_t)b * TLEN + t) * 2 + 0] = hA;
            h1[((size_t)b * TLEN + (TLEN - 1 - t)) * 2 + 1] = hB;
        }
        xA = xAn; xB = xBn;
    }
}

__global__ __launch_bounds__(256) void mean_kernel(
    const float2* __restrict__ h1, float* __restrict__ out)
{
    int i = blockIdx.x * 256 + threadIdx.x;
    if (i < BATCH * TLEN) {
        float2 v = h1[i];
        out[i] = 0.5f * (v.x + v.y);
    }
}

// ===========================================================================
extern "C" void kernel_launch(void* const* d_in, const int* in_sizes, int n_in,
                              void* d_out, int out_size, void* d_ws, size_t ws_size,
                              hipStream_t stream)
{
    const float* ccba_num = (const float*)d_in[0];
    const int*   ccba_bi  = (const int*)d_in[1];
    const int*   ccba_ti  = (const int*)d_in[2];
    const float* ccba_W   = (const float*)d_in[3];
    const float* ccba_b   = (const float*)d_in[4];
    const float* cdtx_num = (const float*)d_in[5];
    const int*   cdtx_cat = (const int*)d_in[6];
    const float* cdtx_tab = (const float*)d_in[7];
    const int*   cdtx_bi  = (const int*)d_in[8];
    const int*   cdtx_ti  = (const int*)d_in[9];
    const float* cdtx_W   = (const float*)d_in[10];
    const float* cdtx_b   = (const float*)d_in[11];
    const float* cust_num = (const float*)d_in[12];
    const int*   cust_cat = (const int*)d_in[13];
    const float* cust_tab = (const float*)d_in[14];
    const int*   cust_bi  = (const int*)d_in[15];
    const int*   cust_ti  = (const int*)d_in[16];
    const float* cust_W   = (const float*)d_in[17];
    const float* cust_b   = (const float*)d_in[18];
    const float* dp_num   = (const float*)d_in[19];
    const int*   dp_cat   = (const int*)d_in[20];
    const float* dp_tab   = (const float*)d_in[21];
    const int*   dp_bi    = (const int*)d_in[22];
    const int*   dp_ti    = (const int*)d_in[23];
    const float* dp_W     = (const float*)d_in[24];
    const float* dp_b     = (const float*)d_in[25];
    const float* remit_num = (const float*)d_in[26];
    const int*   remit_cat = (const int*)d_in[27];
    const float* remit_tab = (const float*)d_in[28];
    const int*   remit_bi  = (const int*)d_in[29];
    const int*   remit_ti  = (const int*)d_in[30];
    const float* remit_W   = (const float*)d_in[31];
    const float* remit_b   = (const float*)d_in[32];
    const float* Wih0 = (const float*)d_in[33];
    const float* Whh0 = (const float*)d_in[34];
    const float* Whr0 = (const float*)d_in[35];
    const float* bih0 = (const float*)d_in[36];
    const float* bhh0 = (const float*)d_in[37];
    const float* Wih1 = (const float*)d_in[38];
    const float* Whh1 = (const float*)d_in[39];
    const float* Whr1 = (const float*)d_in[40];
    const float* bih1 = (const float*)d_in[41];
    const float* bhh1 = (const float*)d_in[42];

    float* out = (float*)d_out;

    // Workspace: wp (266,240) | map (2,048,000) | h0 (4,096,000) | h1 (4,096,000)
    char* ws = (char*)d_ws;
    float* wp  = (float*)ws;
    int*   map = (int*)  (ws + 266240ull);
    float* h0  = (float*)(ws + 266240ull + 2048000ull);
    float* h1  = (float*)(ws + 266240ull + 2048000ull + 4096000ull);

    compose_kernel<<<130, 512, 0, stream>>>(
        ccba_W, ccba_b, cdtx_W, cdtx_b, cust_W, cust_b,
        dp_W, dp_b, remit_W, remit_b, Wih0, bih0, bhh0, wp);

    map_build_kernel<<<dim3(NEVS / 256, 5), 256, 0, stream>>>(
        ccba_bi, ccba_ti, cdtx_bi, cdtx_ti, cust_bi, cust_ti,
        dp_bi, dp_ti, remit_bi, remit_ti, map);

    fused0_kernel<<<2 * BATCH, 512, 0, stream>>>(
        ccba_num,
        cdtx_num, cdtx_cat, cdtx_tab,
        cust_num, cust_cat, cust_tab,
        dp_num, dp_cat, dp_tab,
        remit_num, remit_cat, remit_tab,
        wp, map, Whh0, Whr0, h0);

    lstm1_kernel<<<250, 256, 0, stream>>>(h0, Wih1, Whh1, Whr1, bih1, bhh1, h1);
    mean_kernel<<<(BATCH * TLEN + 255) / 256, 256, 0, stream>>>((const float2*)h1, out);
}